// Round 9
// baseline (408.445 us; speedup 1.0000x reference)
//
#include <hip/hip_runtime.h>
#include <hip/hip_bf16.h>

typedef __attribute__((ext_vector_type(8))) short bf16x8;
typedef __attribute__((ext_vector_type(4))) float f32x4;

#define LDSG(g, l) __builtin_amdgcn_global_load_lds(                      \
    (const __attribute__((address_space(1))) void*)(g),                   \
    (__attribute__((address_space(3))) void*)(l), 16, 0, 0)

#define LOG2E 1.44269504088896f
#define RELSC 0.180336880111112f   /* 0.125 * log2(e) */

// ---------------- kernel 1: fp32 -> bf16 convert (hidden + Wq|Wk|Wv) --------
__global__ __launch_bounds__(256) void cvt_kernel(
    const float* __restrict__ hs,
    const float* __restrict__ wq, const float* __restrict__ wk,
    const float* __restrict__ wv,
    __hip_bfloat16* __restrict__ hbf, __hip_bfloat16* __restrict__ wbf)
{
  const int NH = (4 * 1024 * 1024) / 4;   // hidden quads
  const int NW = (1024 * 1024) / 4;       // per-W quads
  int i = blockIdx.x * 256 + threadIdx.x; // exact grid: NH + 3*NW quads
  float4 v;
  __hip_bfloat16* dst;
  if (i < NH) {
    v = ((const float4*)hs)[i];
    dst = hbf + (size_t)i * 4;
  } else {
    int j = i - NH;
    int which = j / NW, r = j - which * NW;
    const float* src = which == 0 ? wq : (which == 1 ? wk : wv);
    v = ((const float4*)src)[r];
    dst = wbf + (size_t)j * 4;
  }
  union { ushort4 u; __hip_bfloat16 b[4]; } o;
  o.b[0] = __float2bfloat16(v.x);
  o.b[1] = __float2bfloat16(v.y);
  o.b[2] = __float2bfloat16(v.z);
  o.b[3] = __float2bfloat16(v.w);
  *((ushort4*)dst) = o.u;
}

// ---------------- kernel 2: QKV GEMM  C[4096][3072] = A[4096][1024] @ W^T ---
// q scaled by 0.125*log2e, stored [b,h,s,d].
// k/v written PRE-FRAGMENTED in MFMA A-operand order per (bh, ktile):
//   K  chunk (ks*4+ct)*64+lane holds K[k=ct*16+(lane&15)][d=ks*32+(lane>>4)*8+e]
//   V^T chunk (ks*4+dt)*64+lane holds V[k=ks*32+(lane>>4)*8+e][d=dt*16+(lane&15)]
// so attention loads are fully contiguous 1KB instructions.
__global__ __launch_bounds__(256) void qkv_gemm(
    const __hip_bfloat16* __restrict__ A,  // [4096][1024]
    const __hip_bfloat16* __restrict__ W,  // [3072][1024] (q,k,v stacked)
    const float* __restrict__ bq, const float* __restrict__ bk,
    const float* __restrict__ bv,
    __hip_bfloat16* __restrict__ qo, __hip_bfloat16* __restrict__ ko,
    __hip_bfloat16* __restrict__ vo)
{
  const int K = 1024;
  __shared__ __hip_bfloat16 As[128 * 64];
  __shared__ __hip_bfloat16 Bs[128 * 64];
  const int bid = blockIdx.x;
  const int bm = bid & 31, bn = bid >> 5;
  const int m0 = bm * 128, n0 = bn * 128;
  const int tid = threadIdx.x, wid = tid >> 6, lane = tid & 63;
  const int wm = wid >> 1, wn = wid & 1;

  f32x4 acc[4][4] = {};

  const int srow = lane >> 3;              // 0..7 (row within 8-row group)
  const int schunk = (lane & 7) ^ srow;    // swizzled 16B-chunk in row

  for (int k0 = 0; k0 < K; k0 += 64) {
#pragma unroll
    for (int p = 0; p < 4; ++p) {
      int r = (wid * 4 + p) * 8 + srow;    // 0..127
      LDSG(&A[(size_t)(m0 + r) * K + k0 + schunk * 8], &As[(wid * 4 + p) * 512]);
      LDSG(&W[(size_t)(n0 + r) * K + k0 + schunk * 8], &Bs[(wid * 4 + p) * 512]);
    }
    __syncthreads();
#pragma unroll
    for (int ks = 0; ks < 2; ++ks) {
      bf16x8 af[4], bfr[4];
#pragma unroll
      for (int mi = 0; mi < 4; ++mi) {
        int row = wm * 64 + mi * 16 + (lane & 15);
        int slot = (ks * 4 + (lane >> 4)) ^ (lane & 7);
        af[mi] = *(const bf16x8*)((const char*)As + row * 128 + slot * 16);
      }
#pragma unroll
      for (int ni = 0; ni < 4; ++ni) {
        int row = wn * 64 + ni * 16 + (lane & 15);
        int slot = (ks * 4 + (lane >> 4)) ^ (lane & 7);
        bfr[ni] = *(const bf16x8*)((const char*)Bs + row * 128 + slot * 16);
      }
#pragma unroll
      for (int mi = 0; mi < 4; ++mi)
#pragma unroll
        for (int ni = 0; ni < 4; ++ni)
          acc[mi][ni] = __builtin_amdgcn_mfma_f32_16x16x32_bf16(
              af[mi], bfr[ni], acc[mi][ni], 0, 0, 0);
    }
    __syncthreads();
  }

  // epilogue. C/D layout: col = lane&15, row = (lane>>4)*4+j.
#pragma unroll
  for (int ni = 0; ni < 4; ++ni) {
    int n = n0 + wn * 64 + ni * 16 + (lane & 15);
    int which = n >> 10;         // 0=q 1=k 2=v (uniform per block)
    int h = (n >> 6) & 15;
    int d = n & 63;
    const float* bias = which == 0 ? bq : (which == 1 ? bk : bv);
    float bval = bias[n & 1023];
    if (which == 0) {
      // q: [b,h,s,d], pre-scaled by 0.125*log2e
#pragma unroll
      for (int mi = 0; mi < 4; ++mi) {
#pragma unroll
        for (int j = 0; j < 4; ++j) {
          int m = m0 + wm * 64 + mi * 16 + (lane >> 4) * 4 + j;
          int b = m >> 10, s = m & 1023;
          float val = (acc[mi][ni][j] + bval) * RELSC;
          qo[(((size_t)(b * 16 + h) << 10) + s) * 64 + d] = __float2bfloat16(val);
        }
      }
    } else if (which == 1) {
      // K fragment store (scalar scatter)
      int dks = d >> 5, dlg = (d >> 3) & 3, de = d & 7;
#pragma unroll
      for (int mi = 0; mi < 4; ++mi) {
#pragma unroll
        for (int j = 0; j < 4; ++j) {
          int m = m0 + wm * 64 + mi * 16 + (lane >> 4) * 4 + j;
          int b = m >> 10, s = m & 1023;
          size_t idx = ((((size_t)(b * 16 + h)) * 16 + (s >> 6)) * 512 +
                        (size_t)((dks * 4 + ((s >> 4) & 3)) * 64 + (s & 15) +
                                 16 * dlg)) * 8 + de;
          ko[idx] = __float2bfloat16(acc[mi][ni][j] + bval);
        }
      }
    } else {
      // V^T fragment store (ushort4: 4 consecutive k -> consecutive e)
      int dt = d >> 4, dl15 = d & 15;
#pragma unroll
      for (int mi = 0; mi < 4; ++mi) {
        int m = m0 + wm * 64 + mi * 16 + (lane >> 4) * 4;  // k0 (mod 4 == 0)
        int b = m >> 10, k = m & 1023;
        int kt = k >> 6, kks = (k >> 5) & 1, klg = (k >> 3) & 3, ke = k & 7;
        union { ushort4 u; __hip_bfloat16 bb[4]; } o;
#pragma unroll
        for (int j = 0; j < 4; ++j)
          o.bb[j] = __float2bfloat16(acc[mi][ni][j] + bval);
        size_t idx = ((((size_t)(b * 16 + h)) * 16 + kt) * 512 +
                      (size_t)((kks * 4 + dt) * 64 + dl15 + 16 * klg)) * 8 + ke;
        *(ushort4*)&vo[idx] = o.u;
      }
    }
  }
}

// ---------------- kernel 3: producer/consumer flash attention v2 ------------
// 512 threads = 8 waves. Waves 4-7 STREAM rel (+mask) via global_load_lds and
// __syncthreads (its implicit vmcnt(0) drain IS the ready handshake).
// Waves 0-3 COMPUTE with RAW s_barrier (no drain) so their K/V(t+1) register
// prefetch — issued right after each barrier — stays in flight for a full
// period and lands before body t+1. Consumer bodies are then pure compute;
// the barrier rhythm is set by the rel HBM stream.
__global__ __launch_bounds__(512, 4) void attn_kernel(
    const __hip_bfloat16* __restrict__ qg, const __hip_bfloat16* __restrict__ kf,
    const __hip_bfloat16* __restrict__ vf,
    const float* __restrict__ rel1, const float* __restrict__ rel2,
    const float* __restrict__ mask, float* __restrict__ out)
{
  __shared__ float Rbuf[4][2][2][16][64];   // [cw][buf][rel][row][k] 64 KB
  __shared__ float Ml[1024];                // mask*log2e - 32, 4 KB
  __shared__ __hip_bfloat16 Ps[4][16 * 64]; // P transpose bounce, 8 KB

  const int bid = blockIdx.x;
  const int bh = bid & 63, qt = bid >> 6;   // bid%8==bh%8 -> bh pinned to XCD
  const int b = bh >> 4, h = bh & 15;
  const int tid = threadIdx.x, wid = tid >> 6, lane = tid & 63;
  const int lg = lane >> 4, ln15 = lane & 15;

  const size_t qbase = (size_t)bh << 16;    // bh * 1024 * 64
  const size_t fbase = (size_t)bh << 16;    // frag elems per bh

  if (wid >= 4) {
    // ------------------------- streamer wave ------------------------------
    const int cw = wid - 4;
    const int q0c = qt * 64 + cw * 16;
    const int r4 = lane >> 4, c15 = lane & 15;
    const float* relw1 = rel1 + ((size_t)bh << 20);
    const float* relw2 = rel2 + ((size_t)bh << 20);

    // mask stage (4 waves x 64 lanes x 4 floats): Ml = mask*log2e - 32
    {
      int i = cw * 64 + lane;               // 0..255
      float4 mv = *(const float4*)&mask[((size_t)b << 10) + i * 4];
      float4 sm;
      sm.x = mv.x * LOG2E - 32.0f; sm.y = mv.y * LOG2E - 32.0f;
      sm.z = mv.z * LOG2E - 32.0f; sm.w = mv.w * LOG2E - 32.0f;
      *(float4*)&Ml[i * 4] = sm;
    }

    // prologue: tile 0 -> buf 0
#pragma unroll
    for (int p = 0; p < 4; ++p) {
      int rg = 4 * p + r4;
      int cg = c15 ^ (rg & 7);
      LDSG(&relw1[(size_t)(q0c + rg) * 1024 + cg * 4], &Rbuf[cw][0][0][4 * p][0]);
      LDSG(&relw2[(size_t)(q0c + rg) * 1024 + cg * 4], &Rbuf[cw][0][1][4 * p][0]);
    }
    __syncthreads();                        // barrier 0 (drains mask + tile0)

    for (int t = 0; t < 15; ++t) {
      int buf = (t + 1) & 1;
      int kb = (t + 1) * 64;
#pragma unroll
      for (int p = 0; p < 4; ++p) {
        int rg = 4 * p + r4;
        int cg = c15 ^ (rg & 7);
        LDSG(&relw1[(size_t)(q0c + rg) * 1024 + kb + cg * 4],
             &Rbuf[cw][buf][0][4 * p][0]);
        LDSG(&relw2[(size_t)(q0c + rg) * 1024 + kb + cg * 4],
             &Rbuf[cw][buf][1][4 * p][0]);
      }
      __syncthreads();                      // barrier t+1 (vmcnt auto-drained)
    }
    return;                                 // consumers finish body 15 alone
  }

  // -------------------------- consumer wave -------------------------------
  const int q0 = qt * 64 + wid * 16;

  // Q as B-operand fragment: col=ln15=q, contraction d = ks*32 + lg*8 + jj
  bf16x8 qf[2];
  qf[0] = *(const bf16x8*)&qg[qbase + (size_t)(q0 + ln15) * 64 + lg * 8];
  qf[1] = *(const bf16x8*)&qg[qbase + (size_t)(q0 + ln15) * 64 + 32 + lg * 8];

  // prologue K/V(0) register prefetch (stays in flight across raw barrier)
  bf16x8 kA[8], vA[8], kB[8], vB[8];
#pragma unroll
  for (int i = 0; i < 8; ++i)
    kA[i] = *(const bf16x8*)&kf[fbase + i * 512 + lane * 8];
#pragma unroll
  for (int i = 0; i < 8; ++i)
    vA[i] = *(const bf16x8*)&vf[fbase + i * 512 + lane * 8];

  f32x4 accO[4] = {};
  float lrun = 0.f;

  __builtin_amdgcn_s_barrier();             // barrier 0 (raw: no drain)

#define CBODY(KC, VC, KN, VN, T, PF) do {                                   \
    if (PF) {                                                               \
      _Pragma("unroll") for (int i = 0; i < 8; ++i)                         \
        KN[i] = *(const bf16x8*)&kf[fbase + (size_t)((T) + 1) * 4096 +      \
                                    i * 512 + lane * 8];                    \
      _Pragma("unroll") for (int i = 0; i < 8; ++i)                         \
        VN[i] = *(const bf16x8*)&vf[fbase + (size_t)((T) + 1) * 4096 +      \
                                    i * 512 + lane * 8];                    \
      __builtin_amdgcn_sched_barrier(0);                                    \
    }                                                                       \
    f32x4 st[4] = {};                                                       \
    _Pragma("unroll") for (int ks = 0; ks < 2; ++ks)                        \
      _Pragma("unroll") for (int ct = 0; ct < 4; ++ct)                      \
        st[ct] = __builtin_amdgcn_mfma_f32_16x16x32_bf16(                   \
            KC[ks * 4 + ct], qf[ks], st[ct], 0, 0, 0);                      \
    const char* Rb1 = (const char*)&Rbuf[wid][(T) & 1][0][0][0];            \
    const char* Rb2 = (const char*)&Rbuf[wid][(T) & 1][1][0][0];            \
    float p_[4][4];                                                         \
    _Pragma("unroll") for (int ct = 0; ct < 4; ++ct) {                      \
      int cc = ((ct * 4 + lg) ^ (ln15 & 7)) * 16;                           \
      float4 rv1 = *(const float4*)(Rb1 + ln15 * 256 + cc);                 \
      float4 rv2 = *(const float4*)(Rb2 + ln15 * 256 + cc);                 \
      float4 mv = *(const float4*)&Ml[(T) * 64 + ct * 16 + lg * 4];         \
      _Pragma("unroll") for (int j = 0; j < 4; ++j) {                       \
        float sv = st[ct][j] +                                              \
                   RELSC * (((const float*)&rv1)[j] +                       \
                            ((const float*)&rv2)[j]) +                      \
                   ((const float*)&mv)[j];                                  \
        float e = __builtin_amdgcn_exp2f(sv);                               \
        p_[ct][j] = e; lrun += e;                                           \
      }                                                                     \
    }                                                                       \
    __hip_bfloat16* Pw = &Ps[wid][0];                                       \
    _Pragma("unroll") for (int ct = 0; ct < 4; ++ct) {                      \
      union { ushort4 u; __hip_bfloat16 bb[4]; } w;                         \
      _Pragma("unroll") for (int j = 0; j < 4; ++j)                         \
        w.bb[j] = __float2bfloat16(p_[ct][j]);                              \
      *(ushort4*)((char*)Pw + ln15 * 128 +                                  \
                  ((ct * 32 + lg * 8) ^ ((ln15 & 7) << 4))) = w.u;          \
    }                                                                       \
    bf16x8 pt[2];                                                           \
    pt[0] = *(const bf16x8*)((const char*)Pw + ln15 * 128 +                 \
                             ((lg * 16) ^ ((ln15 & 7) << 4)));              \
    pt[1] = *(const bf16x8*)((const char*)Pw + ln15 * 128 +                 \
                             ((64 + lg * 16) ^ ((ln15 & 7) << 4)));         \
    _Pragma("unroll") for (int ks = 0; ks < 2; ++ks)                        \
      _Pragma("unroll") for (int dt = 0; dt < 4; ++dt)                      \
        accO[dt] = __builtin_amdgcn_mfma_f32_16x16x32_bf16(                 \
            VC[ks * 4 + dt], pt[ks], accO[dt], 0, 0, 0);                    \
    if ((T) < 15) __builtin_amdgcn_s_barrier();                             \
  } while (0)

  for (int t = 0; t < 7; ++t) {
    CBODY(kA, vA, kB, vB, 2 * t, 1);
    CBODY(kB, vB, kA, vA, 2 * t + 1, 1);
  }
  CBODY(kA, vA, kB, vB, 14, 1);
  CBODY(kB, vB, kA, vA, 15, 0);

  // single final denominator reduce (q = ln15 column preserved)
  lrun += __shfl_xor(lrun, 16, 64);
  lrun += __shfl_xor(lrun, 32, 64);
  float rl = 1.0f / lrun;

  // epilogue: lane holds ctx^T[d=dt*16+lg*4+j][q=q0+ln15]; out fp32 [b,s,C]
#pragma unroll
  for (int dt = 0; dt < 4; ++dt) {
    float4 o;
    o.x = accO[dt][0] * rl;
    o.y = accO[dt][1] * rl;
    o.z = accO[dt][2] * rl;
    o.w = accO[dt][3] * rl;
    *(float4*)&out[((size_t)(b * 1024 + q0 + ln15)) * 1024 + h * 64 +
                   dt * 16 + lg * 4] = o;
  }
}

// ---------------------------------------------------------------------------
extern "C" void kernel_launch(void* const* d_in, const int* in_sizes, int n_in,
                              void* d_out, int out_size, void* d_ws,
                              size_t ws_size, hipStream_t stream) {
  const float* hs   = (const float*)d_in[0];
  const float* mask = (const float*)d_in[1];
  const float* rel1 = (const float*)d_in[2];
  const float* rel2 = (const float*)d_in[3];
  const float* Wq   = (const float*)d_in[4];
  const float* bq   = (const float*)d_in[5];
  const float* Wk   = (const float*)d_in[6];
  const float* bk   = (const float*)d_in[7];
  const float* Wv   = (const float*)d_in[8];
  const float* bv   = (const float*)d_in[9];

  char* ws = (char*)d_ws;
  __hip_bfloat16* hbf = (__hip_bfloat16*)(ws);              // 8 MB
  __hip_bfloat16* wbf = (__hip_bfloat16*)(ws + 8388608);    // 6 MB
  __hip_bfloat16* qb  = (__hip_bfloat16*)(ws + 14680064);   // 8 MB
  __hip_bfloat16* kfb = (__hip_bfloat16*)(ws + 23068672);   // 8 MB (K frag)
  __hip_bfloat16* vfb = (__hip_bfloat16*)(ws + 31457280);   // 8 MB (V^T frag)

  cvt_kernel<<<7168, 256, 0, stream>>>(hs, Wq, Wk, Wv, hbf, wbf);
  qkv_gemm<<<768, 256, 0, stream>>>(hbf, wbf, bq, bk, bv, qb, kfb, vfb);
  attn_kernel<<<1024, 512, 0, stream>>>(qb, kfb, vfb, rel1, rel2, mask,
                                        (float*)d_out);
}

// Round 10
// 182.121 us; speedup vs baseline: 2.2427x; 2.2427x over previous
//
#include <hip/hip_runtime.h>
#include <hip/hip_bf16.h>

typedef __attribute__((ext_vector_type(8))) short bf16x8;
typedef __attribute__((ext_vector_type(4))) float f32x4;

#define LDSG(g, l) __builtin_amdgcn_global_load_lds(                      \
    (const __attribute__((address_space(1))) void*)(g),                   \
    (__attribute__((address_space(3))) void*)(l), 16, 0, 0)

#define LOG2E 1.44269504088896f
#define RELSC 0.180336880111112f   /* 0.125 * log2(e) */

// ---------------- kernel 1: fp32 -> bf16 convert (hidden + Wq|Wk|Wv) --------
__global__ __launch_bounds__(256) void cvt_kernel(
    const float* __restrict__ hs,
    const float* __restrict__ wq, const float* __restrict__ wk,
    const float* __restrict__ wv,
    __hip_bfloat16* __restrict__ hbf, __hip_bfloat16* __restrict__ wbf)
{
  const int NH = (4 * 1024 * 1024) / 4;   // hidden quads
  const int NW = (1024 * 1024) / 4;       // per-W quads
  int i = blockIdx.x * 256 + threadIdx.x; // exact grid: NH + 3*NW quads
  float4 v;
  __hip_bfloat16* dst;
  if (i < NH) {
    v = ((const float4*)hs)[i];
    dst = hbf + (size_t)i * 4;
  } else {
    int j = i - NH;
    int which = j / NW, r = j - which * NW;
    const float* src = which == 0 ? wq : (which == 1 ? wk : wv);
    v = ((const float4*)src)[r];
    dst = wbf + (size_t)j * 4;
  }
  union { ushort4 u; __hip_bfloat16 b[4]; } o;
  o.b[0] = __float2bfloat16(v.x);
  o.b[1] = __float2bfloat16(v.y);
  o.b[2] = __float2bfloat16(v.z);
  o.b[3] = __float2bfloat16(v.w);
  *((ushort4*)dst) = o.u;
}

// ---------------- kernel 2: QKV GEMM  C[4096][3072] = A[4096][1024] @ W^T ---
// q scaled by 0.125*log2e, stored [b,h,s,d].
// k/v written PRE-FRAGMENTED in MFMA A-operand order per (bh, ktile):
//   K  chunk (ks*4+ct)*64+lane holds K[k=ct*16+(lane&15)][d=ks*32+(lane>>4)*8+e]
//   V^T chunk (ks*4+dt)*64+lane holds V[k=ks*32+(lane>>4)*8+e][d=dt*16+(lane&15)]
// so attention loads are fully contiguous 1KB instructions.
__global__ __launch_bounds__(256) void qkv_gemm(
    const __hip_bfloat16* __restrict__ A,  // [4096][1024]
    const __hip_bfloat16* __restrict__ W,  // [3072][1024] (q,k,v stacked)
    const float* __restrict__ bq, const float* __restrict__ bk,
    const float* __restrict__ bv,
    __hip_bfloat16* __restrict__ qo, __hip_bfloat16* __restrict__ ko,
    __hip_bfloat16* __restrict__ vo)
{
  const int K = 1024;
  __shared__ __hip_bfloat16 As[128 * 64];
  __shared__ __hip_bfloat16 Bs[128 * 64];
  const int bid = blockIdx.x;
  const int bm = bid & 31, bn = bid >> 5;
  const int m0 = bm * 128, n0 = bn * 128;
  const int tid = threadIdx.x, wid = tid >> 6, lane = tid & 63;
  const int wm = wid >> 1, wn = wid & 1;

  f32x4 acc[4][4] = {};

  const int srow = lane >> 3;              // 0..7 (row within 8-row group)
  const int schunk = (lane & 7) ^ srow;    // swizzled 16B-chunk in row

  for (int k0 = 0; k0 < K; k0 += 64) {
#pragma unroll
    for (int p = 0; p < 4; ++p) {
      int r = (wid * 4 + p) * 8 + srow;    // 0..127
      LDSG(&A[(size_t)(m0 + r) * K + k0 + schunk * 8], &As[(wid * 4 + p) * 512]);
      LDSG(&W[(size_t)(n0 + r) * K + k0 + schunk * 8], &Bs[(wid * 4 + p) * 512]);
    }
    __syncthreads();
#pragma unroll
    for (int ks = 0; ks < 2; ++ks) {
      bf16x8 af[4], bfr[4];
#pragma unroll
      for (int mi = 0; mi < 4; ++mi) {
        int row = wm * 64 + mi * 16 + (lane & 15);
        int slot = (ks * 4 + (lane >> 4)) ^ (lane & 7);
        af[mi] = *(const bf16x8*)((const char*)As + row * 128 + slot * 16);
      }
#pragma unroll
      for (int ni = 0; ni < 4; ++ni) {
        int row = wn * 64 + ni * 16 + (lane & 15);
        int slot = (ks * 4 + (lane >> 4)) ^ (lane & 7);
        bfr[ni] = *(const bf16x8*)((const char*)Bs + row * 128 + slot * 16);
      }
#pragma unroll
      for (int mi = 0; mi < 4; ++mi)
#pragma unroll
        for (int ni = 0; ni < 4; ++ni)
          acc[mi][ni] = __builtin_amdgcn_mfma_f32_16x16x32_bf16(
              af[mi], bfr[ni], acc[mi][ni], 0, 0, 0);
    }
    __syncthreads();
  }

  // epilogue. C/D layout: col = lane&15, row = (lane>>4)*4+j.
#pragma unroll
  for (int ni = 0; ni < 4; ++ni) {
    int n = n0 + wn * 64 + ni * 16 + (lane & 15);
    int which = n >> 10;         // 0=q 1=k 2=v (uniform per block)
    int h = (n >> 6) & 15;
    int d = n & 63;
    const float* bias = which == 0 ? bq : (which == 1 ? bk : bv);
    float bval = bias[n & 1023];
    if (which == 0) {
      // q: [b,h,s,d], pre-scaled by 0.125*log2e
#pragma unroll
      for (int mi = 0; mi < 4; ++mi) {
#pragma unroll
        for (int j = 0; j < 4; ++j) {
          int m = m0 + wm * 64 + mi * 16 + (lane >> 4) * 4 + j;
          int b = m >> 10, s = m & 1023;
          float val = (acc[mi][ni][j] + bval) * RELSC;
          qo[(((size_t)(b * 16 + h) << 10) + s) * 64 + d] = __float2bfloat16(val);
        }
      }
    } else if (which == 1) {
      // K fragment store (scalar scatter)
      int dks = d >> 5, dlg = (d >> 3) & 3, de = d & 7;
#pragma unroll
      for (int mi = 0; mi < 4; ++mi) {
#pragma unroll
        for (int j = 0; j < 4; ++j) {
          int m = m0 + wm * 64 + mi * 16 + (lane >> 4) * 4 + j;
          int b = m >> 10, s = m & 1023;
          size_t idx = ((((size_t)(b * 16 + h)) * 16 + (s >> 6)) * 512 +
                        (size_t)((dks * 4 + ((s >> 4) & 3)) * 64 + (s & 15) +
                                 16 * dlg)) * 8 + de;
          ko[idx] = __float2bfloat16(acc[mi][ni][j] + bval);
        }
      }
    } else {
      // V^T fragment store (ushort4: 4 consecutive k -> consecutive e)
      int dt = d >> 4, dl15 = d & 15;
#pragma unroll
      for (int mi = 0; mi < 4; ++mi) {
        int m = m0 + wm * 64 + mi * 16 + (lane >> 4) * 4;  // k0 (mod 4 == 0)
        int b = m >> 10, k = m & 1023;
        int kt = k >> 6, kks = (k >> 5) & 1, klg = (k >> 3) & 3, ke = k & 7;
        union { ushort4 u; __hip_bfloat16 bb[4]; } o;
#pragma unroll
        for (int j = 0; j < 4; ++j)
          o.bb[j] = __float2bfloat16(acc[mi][ni][j] + bval);
        size_t idx = ((((size_t)(b * 16 + h)) * 16 + kt) * 512 +
                      (size_t)((kks * 4 + dt) * 64 + dl15 + 16 * klg)) * 8 + ke;
        *(ushort4*)&vo[idx] = o.u;
      }
    }
  }
}

// ---------------- kernel 3: deep-pipelined producer/consumer attention ------
// 256 threads = 4 waves: waves 0-1 COMPUTE (16 q-rows each), waves 2-3 STREAM
// rel for consumer (wid-2) through a 4-DEEP LDS ring, running 3 tiles ahead
// with counted vmcnt (tile t+1 complete <=> vmcnt(16); t+2/t+3 stay in
// flight across RAW s_barriers). This keeps 16-24KB outstanding per streamer
// wave continuously -> HBM concurrency instead of 1-deep latency-bound r8.
// Consumers: raw barriers only, K/V register double-buffer prefetched one
// body ahead (VGPR cap 256 via __launch_bounds__(256,2) -- r9 spilled at 128).
__global__ __launch_bounds__(256, 2) void attn_kernel(
    const __hip_bfloat16* __restrict__ qg, const __hip_bfloat16* __restrict__ kf,
    const __hip_bfloat16* __restrict__ vf,
    const float* __restrict__ rel1, const float* __restrict__ rel2,
    const float* __restrict__ mask, float* __restrict__ out)
{
  __shared__ float Rbuf[2][4][2][16][64];   // [cw][ring][rel][row][k] 64 KB
  __shared__ float Ml[1024];                // mask*log2e - 32, 4 KB
  __shared__ __hip_bfloat16 Ps[2][16 * 64]; // P transpose bounce, 4 KB

  const int bid = blockIdx.x;
  const int bh = bid & 63, qt = bid >> 6;   // bid%8==bh%8 -> bh pinned to XCD
  const int b = bh >> 4, h = bh & 15;
  const int tid = threadIdx.x, wid = tid >> 6, lane = tid & 63;
  const int lg = lane >> 4, ln15 = lane & 15;

  const size_t qbase = (size_t)bh << 16;    // bh * 1024 * 64
  const size_t fbase = (size_t)bh << 16;    // frag elems per bh

  if (wid >= 2) {
    // ------------------------- streamer wave ------------------------------
    const int cw = wid - 2;
    const int q0c = qt * 32 + cw * 16;
    const int r4 = lane >> 4, c15 = lane & 15;
    const float* relw1 = rel1 + ((size_t)bh << 20);
    const float* relw2 = rel2 + ((size_t)bh << 20);

    // mask stage: 128 lanes x 8 floats; Ml = mask*log2e - 32
    {
      int i = cw * 64 + lane;               // 0..127
      float4 m0 = *(const float4*)&mask[((size_t)b << 10) + i * 8];
      float4 m1 = *(const float4*)&mask[((size_t)b << 10) + i * 8 + 4];
      float4 s0, s1;
      s0.x = m0.x * LOG2E - 32.0f; s0.y = m0.y * LOG2E - 32.0f;
      s0.z = m0.z * LOG2E - 32.0f; s0.w = m0.w * LOG2E - 32.0f;
      s1.x = m1.x * LOG2E - 32.0f; s1.y = m1.y * LOG2E - 32.0f;
      s1.z = m1.z * LOG2E - 32.0f; s1.w = m1.w * LOG2E - 32.0f;
      *(float4*)&Ml[i * 8] = s0;
      *(float4*)&Ml[i * 8 + 4] = s1;
    }

#define SREL(T) do {                                                        \
    _Pragma("unroll") for (int p = 0; p < 4; ++p) {                         \
      int rg = 4 * p + r4;                                                  \
      int cg = c15 ^ (rg & 7);                                              \
      LDSG(&relw1[(size_t)(q0c + rg) * 1024 + (T) * 64 + cg * 4],           \
           &Rbuf[cw][(T) & 3][0][4 * p][0]);                                \
      LDSG(&relw2[(size_t)(q0c + rg) * 1024 + (T) * 64 + cg * 4],           \
           &Rbuf[cw][(T) & 3][1][4 * p][0]);                                \
    } } while (0)

    SREL(0); SREL(1); SREL(2);              // 3 tiles in flight
    __builtin_amdgcn_sched_barrier(0);
    asm volatile("s_waitcnt vmcnt(16) lgkmcnt(0)" ::: "memory"); // tile0+mask
    __builtin_amdgcn_s_barrier();           // barrier 0: consumers use tile 0

#pragma unroll
    for (int t = 0; t <= 12; ++t) {
      SREL(t + 3);                          // refill ring, 3 ahead
      __builtin_amdgcn_sched_barrier(0);
      asm volatile("s_waitcnt vmcnt(16)" ::: "memory");  // tile t+1 done
      __builtin_amdgcn_s_barrier();         // barrier t+1
    }
    asm volatile("s_waitcnt vmcnt(8)" ::: "memory");     // tile 14 done
    __builtin_amdgcn_s_barrier();           // barrier 14
    asm volatile("s_waitcnt vmcnt(0)" ::: "memory");     // tile 15 done
    __builtin_amdgcn_s_barrier();           // barrier 15
    return;                                 // consumers finish body 15 alone
  }

  // -------------------------- consumer wave -------------------------------
  const int q0 = qt * 32 + wid * 16;

  // Q as B-operand fragment: col=ln15=q, contraction d = ks*32 + lg*8 + jj
  bf16x8 qf[2];
  qf[0] = *(const bf16x8*)&qg[qbase + (size_t)(q0 + ln15) * 64 + lg * 8];
  qf[1] = *(const bf16x8*)&qg[qbase + (size_t)(q0 + ln15) * 64 + 32 + lg * 8];

  // K/V(0) register prefetch (survives raw barrier; compiler waits at use)
  bf16x8 kA[8], vA[8], kB[8], vB[8];
#pragma unroll
  for (int i = 0; i < 8; ++i)
    kA[i] = *(const bf16x8*)&kf[fbase + i * 512 + lane * 8];
#pragma unroll
  for (int i = 0; i < 8; ++i)
    vA[i] = *(const bf16x8*)&vf[fbase + i * 512 + lane * 8];

  f32x4 accO[4] = {};
  float lrun = 0.f;

  __builtin_amdgcn_s_barrier();             // barrier 0 (raw: no drain)

#define CBODY(KC, VC, KN, VN, T, PF) do {                                   \
    f32x4 st[4] = {};                                                       \
    _Pragma("unroll") for (int ks = 0; ks < 2; ++ks)                        \
      _Pragma("unroll") for (int ct = 0; ct < 4; ++ct)                      \
        st[ct] = __builtin_amdgcn_mfma_f32_16x16x32_bf16(                   \
            KC[ks * 4 + ct], qf[ks], st[ct], 0, 0, 0);                      \
    if (PF) {                                                               \
      _Pragma("unroll") for (int i = 0; i < 8; ++i)                         \
        KN[i] = *(const bf16x8*)&kf[fbase + (size_t)((T) + 1) * 4096 +      \
                                    i * 512 + lane * 8];                    \
      _Pragma("unroll") for (int i = 0; i < 8; ++i)                         \
        VN[i] = *(const bf16x8*)&vf[fbase + (size_t)((T) + 1) * 4096 +      \
                                    i * 512 + lane * 8];                    \
      __builtin_amdgcn_sched_barrier(0);                                    \
    }                                                                       \
    const char* Rb1 = (const char*)&Rbuf[wid][(T) & 3][0][0][0];            \
    const char* Rb2 = (const char*)&Rbuf[wid][(T) & 3][1][0][0];            \
    float p_[4][4];                                                         \
    _Pragma("unroll") for (int ct = 0; ct < 4; ++ct) {                      \
      int cc = ((ct * 4 + lg) ^ (ln15 & 7)) * 16;                           \
      float4 rv1 = *(const float4*)(Rb1 + ln15 * 256 + cc);                 \
      float4 rv2 = *(const float4*)(Rb2 + ln15 * 256 + cc);                 \
      float4 mv = *(const float4*)&Ml[(T) * 64 + ct * 16 + lg * 4];         \
      _Pragma("unroll") for (int j = 0; j < 4; ++j) {                       \
        float sv = st[ct][j] +                                              \
                   RELSC * (((const float*)&rv1)[j] +                       \
                            ((const float*)&rv2)[j]) +                      \
                   ((const float*)&mv)[j];                                  \
        float e = __builtin_amdgcn_exp2f(sv);                               \
        p_[ct][j] = e; lrun += e;                                           \
      }                                                                     \
    }                                                                       \
    __hip_bfloat16* Pw = &Ps[wid][0];                                       \
    _Pragma("unroll") for (int ct = 0; ct < 4; ++ct) {                      \
      union { ushort4 u; __hip_bfloat16 bb[4]; } w;                         \
      _Pragma("unroll") for (int j = 0; j < 4; ++j)                         \
        w.bb[j] = __float2bfloat16(p_[ct][j]);                              \
      *(ushort4*)((char*)Pw + ln15 * 128 +                                  \
                  ((ct * 32 + lg * 8) ^ ((ln15 & 7) << 4))) = w.u;          \
    }                                                                       \
    bf16x8 pt[2];                                                           \
    pt[0] = *(const bf16x8*)((const char*)Pw + ln15 * 128 +                 \
                             ((lg * 16) ^ ((ln15 & 7) << 4)));              \
    pt[1] = *(const bf16x8*)((const char*)Pw + ln15 * 128 +                 \
                             ((64 + lg * 16) ^ ((ln15 & 7) << 4)));         \
    _Pragma("unroll") for (int ks = 0; ks < 2; ++ks)                        \
      _Pragma("unroll") for (int dt = 0; dt < 4; ++dt)                      \
        accO[dt] = __builtin_amdgcn_mfma_f32_16x16x32_bf16(                 \
            VC[ks * 4 + dt], pt[ks], accO[dt], 0, 0, 0);                    \
    if ((T) < 15) __builtin_amdgcn_s_barrier();                             \
  } while (0)

  for (int t = 0; t < 7; ++t) {
    CBODY(kA, vA, kB, vB, 2 * t, 1);
    CBODY(kB, vB, kA, vA, 2 * t + 1, 1);
  }
  CBODY(kA, vA, kB, vB, 14, 1);
  CBODY(kB, vB, kA, vA, 15, 0);

  // single final denominator reduce (q = ln15 column preserved)
  lrun += __shfl_xor(lrun, 16, 64);
  lrun += __shfl_xor(lrun, 32, 64);
  float rl = 1.0f / lrun;

  // epilogue: lane holds ctx^T[d=dt*16+lg*4+j][q=q0+ln15]; out fp32 [b,s,C]
#pragma unroll
  for (int dt = 0; dt < 4; ++dt) {
    float4 o;
    o.x = accO[dt][0] * rl;
    o.y = accO[dt][1] * rl;
    o.z = accO[dt][2] * rl;
    o.w = accO[dt][3] * rl;
    *(float4*)&out[((size_t)(b * 1024 + q0 + ln15)) * 1024 + h * 64 +
                   dt * 16 + lg * 4] = o;
  }
}

// ---------------------------------------------------------------------------
extern "C" void kernel_launch(void* const* d_in, const int* in_sizes, int n_in,
                              void* d_out, int out_size, void* d_ws,
                              size_t ws_size, hipStream_t stream) {
  const float* hs   = (const float*)d_in[0];
  const float* mask = (const float*)d_in[1];
  const float* rel1 = (const float*)d_in[2];
  const float* rel2 = (const float*)d_in[3];
  const float* Wq   = (const float*)d_in[4];
  const float* bq   = (const float*)d_in[5];
  const float* Wk   = (const float*)d_in[6];
  const float* bk   = (const float*)d_in[7];
  const float* Wv   = (const float*)d_in[8];
  const float* bv   = (const float*)d_in[9];

  char* ws = (char*)d_ws;
  __hip_bfloat16* hbf = (__hip_bfloat16*)(ws);              // 8 MB
  __hip_bfloat16* wbf = (__hip_bfloat16*)(ws + 8388608);    // 6 MB
  __hip_bfloat16* qb  = (__hip_bfloat16*)(ws + 14680064);   // 8 MB
  __hip_bfloat16* kfb = (__hip_bfloat16*)(ws + 23068672);   // 8 MB (K frag)
  __hip_bfloat16* vfb = (__hip_bfloat16*)(ws + 31457280);   // 8 MB (V^T frag)

  cvt_kernel<<<7168, 256, 0, stream>>>(hs, Wq, Wk, Wv, hbf, wbf);
  qkv_gemm<<<768, 256, 0, stream>>>(hbf, wbf, bq, bk, bv, qb, kfb, vfb);
  attn_kernel<<<2048, 256, 0, stream>>>(qb, kfb, vfb, rel1, rel2, mask,
                                        (float*)d_out);
}